// Round 2
// baseline (2058.150 us; speedup 1.0000x reference)
//
#include <hip/hip_runtime.h>

#define N_NODES 100000
#define E_EDGES 1000000
#define R_REL   3

__device__ __forceinline__ float lrelu(float x) { return x > 0.f ? x : 0.2f * x; }

// ---------------------------------------------------------------------------
// h = x @ proj_w.T + proj_b ; a_src/a_dst[r][n][hd] = <h[n,hd,:], att[r,hd,:]>
// Block: 256 threads = 2 nodes x 128 outputs, W staged in LDS (padded 129).
// ---------------------------------------------------------------------------
__global__ __launch_bounds__(256) void proj_kernel(
    const float* __restrict__ x, const float* __restrict__ pw,
    const float* __restrict__ pb, const float* __restrict__ att_src,
    const float* __restrict__ att_dst,
    float* __restrict__ h, float* __restrict__ a_src, float* __restrict__ a_dst)
{
    __shared__ float w_s[128][129];
    __shared__ float x_s[2][128];
    __shared__ float h_s[2][128];
    __shared__ float as_s[24][16];
    __shared__ float ad_s[24][16];
    __shared__ float pb_s[128];

    int tid = threadIdx.x;
    for (int i = tid; i < 128 * 128; i += 256) w_s[i >> 7][i & 127] = pw[i];
    if (tid < 128) pb_s[tid] = pb[tid];
    for (int i = tid; i < 24 * 16; i += 256) {
        as_s[i >> 4][i & 15] = att_src[i];
        ad_s[i >> 4][i & 15] = att_dst[i];
    }
    __syncthreads();

    int nn = tid >> 7, j = tid & 127;
    int nBase = blockIdx.x * 128;
    for (int it = 0; it < 64; ++it) {
        int n = nBase + it * 2 + nn;
        if (n < N_NODES) x_s[nn][j] = x[(size_t)n * 128 + j];
        __syncthreads();
        float s0 = 0.f, s1 = 0.f, s2 = 0.f, s3 = 0.f;
        #pragma unroll
        for (int k = 0; k < 128; k += 4) {
            s0 += x_s[nn][k]     * w_s[j][k];
            s1 += x_s[nn][k + 1] * w_s[j][k + 1];
            s2 += x_s[nn][k + 2] * w_s[j][k + 2];
            s3 += x_s[nn][k + 3] * w_s[j][k + 3];
        }
        float acc = ((s0 + s1) + (s2 + s3)) + pb_s[j];
        h_s[nn][j] = acc;
        if (n < N_NODES) h[(size_t)n * 128 + j] = acc;
        __syncthreads();
        if (tid < 48) {
            int nn2 = tid / 24, p = tid % 24;
            int n2 = nBase + it * 2 + nn2;
            if (n2 < N_NODES) {
                int r = p >> 3, hd = p & 7;
                float vs = 0.f, vd = 0.f;
                #pragma unroll
                for (int d = 0; d < 16; ++d) {
                    float hv = h_s[nn2][hd * 16 + d];
                    vs += hv * as_s[p][d];
                    vd += hv * ad_s[p][d];
                }
                a_src[((size_t)r * N_NODES + n2) * 8 + hd] = vs;
                a_dst[((size_t)r * N_NODES + n2) * 8 + hd] = vd;
            }
        }
        __syncthreads();
    }
}

// ---------------------------------------------------------------------------
// CSR build: count degrees (one int atomic per edge).
// ---------------------------------------------------------------------------
__global__ __launch_bounds__(256) void count_kernel(
    const int* __restrict__ e0, const int* __restrict__ e1, const int* __restrict__ e2,
    int* __restrict__ cnt)
{
    int r = blockIdx.y;
    const int* ei = (r == 0) ? e0 : (r == 1) ? e1 : e2;
    int e = blockIdx.x * 256 + threadIdx.x;
    if (e >= E_EDGES) return;
    int col = ei[E_EDGES + e];
    atomicAdd(&cnt[r * N_NODES + col], 1);
}

// ---------------------------------------------------------------------------
// Exclusive scan of degrees -> offsets (+cursor copy). One block per relation.
// Relation r's edges occupy csr_rows[r*E .. (r+1)*E).
// ---------------------------------------------------------------------------
__global__ __launch_bounds__(256) void scan_kernel(
    const int* __restrict__ cnt, int* __restrict__ off, int* __restrict__ cursor)
{
    int r = blockIdx.x;
    int t = threadIdx.x;
    const int CH = (N_NODES + 255) / 256;   // 391
    int lo = t * CH, hi = lo + CH;
    if (hi > N_NODES) hi = N_NODES;
    int s = 0;
    for (int i = lo; i < hi; ++i) s += cnt[r * N_NODES + i];
    __shared__ int part[256];
    part[t] = s;
    __syncthreads();
    for (int d = 1; d < 256; d <<= 1) {
        int v = (t >= d) ? part[t - d] : 0;
        __syncthreads();
        part[t] += v;
        __syncthreads();
    }
    int base = r * E_EDGES + ((t > 0) ? part[t - 1] : 0);
    for (int i = lo; i < hi; ++i) {
        off[r * N_NODES + i] = base;
        cursor[r * N_NODES + i] = base;
        base += cnt[r * N_NODES + i];
    }
}

__global__ __launch_bounds__(256) void fill_kernel(
    const int* __restrict__ e0, const int* __restrict__ e1, const int* __restrict__ e2,
    int* __restrict__ cursor, int* __restrict__ csr_rows)
{
    int r = blockIdx.y;
    const int* ei = (r == 0) ? e0 : (r == 1) ? e1 : e2;
    int e = blockIdx.x * 256 + threadIdx.x;
    if (e >= E_EDGES) return;
    int row = ei[e];
    int col = ei[E_EDGES + e];
    int pos = atomicAdd(&cursor[r * N_NODES + col], 1);
    csr_rows[pos] = row;
}

// ---------------------------------------------------------------------------
// Fused pull + semantic + lin projection. One wave per (relation, node-quad).
// Lane d owns output dims {d, d+64}. exp without max-shift (logits O(1),
// softmax shift-invariant). After computing the out row:
//   - proj_out[r][n][o] = out . lin_w[o]           (wave shuffle-reduce)
//   - red[r][j] += tanh(out . k_w[j] + k_b[j])     (k_w staged in LDS,
//     4 nodes batched per pass to amortize LDS reads)
// outs is never materialized in global memory.
// ---------------------------------------------------------------------------
__global__ __launch_bounds__(256) void pull_kernel(
    const float* __restrict__ h, const float* __restrict__ a_src,
    const float* __restrict__ a_dst, const int* __restrict__ cnt,
    const int* __restrict__ off, const int* __restrict__ csr_rows,
    const float* __restrict__ kw, const float* __restrict__ kb,
    const float* __restrict__ lw,
    float* __restrict__ proj_out, float* __restrict__ red)
{
    __shared__ float kw_s[128][129];   // 66 KB, +1 pad -> 2-way (free)
    __shared__ float out_s[4][4][128]; // 8 KB: [wave][batch][dim]
    __shared__ float kb_s[128];
    __shared__ float lw_s[4][128];

    int tid = threadIdx.x;
    int r = blockIdx.y;
    for (int i = tid; i < 128 * 128; i += 256) kw_s[i >> 7][i & 127] = kw[i];
    if (tid < 128) kb_s[tid] = kb[tid];
    for (int i = tid; i < 512; i += 256) lw_s[i >> 7][i & 127] = lw[i];
    __syncthreads();

    int wave = tid >> 6, lane = tid & 63;
    int h0 = lane >> 4, h1 = h0 + 4;
    float kb0 = kb_s[lane], kb1 = kb_s[64 + lane];
    float sem0 = 0.f, sem1 = 0.f;

    for (int nb = blockIdx.x * 16 + wave * 4; nb < N_NODES; nb += gridDim.x * 16) {
        int nvalid = N_NODES - nb;
        if (nvalid > 4) nvalid = 4;

        for (int i = 0; i < nvalid; ++i) {
            int n = nb + i;
            size_t rn = (size_t)r * N_NODES + n;
            float ad0 = a_dst[rn * 8 + h0];
            float ad1 = a_dst[rn * 8 + h1];
            int deg   = cnt[rn];
            int start = off[rn];
            float acc0 = 0.f, acc1 = 0.f, den0 = 0.f, den1 = 0.f;
            for (int k = 0; k < deg; ++k) {
                int row = csr_rows[start + k];
                size_t rr = (size_t)r * N_NODES + row;
                float e0 = __expf(lrelu(a_src[rr * 8 + h0] + ad0));
                float e1 = __expf(lrelu(a_src[rr * 8 + h1] + ad1));
                const float* hr = h + (size_t)row * 128;
                acc0 += e0 * hr[lane];
                acc1 += e1 * hr[64 + lane];
                den0 += e0;
                den1 += e1;
            }
            float o0 = fmaxf(acc0 / (den0 + 1e-16f), 0.f);
            float o1 = fmaxf(acc1 / (den1 + 1e-16f), 0.f);
            out_s[wave][i][lane]      = o0;
            out_s[wave][i][64 + lane] = o1;

            float p0 = o0 * lw_s[0][lane] + o1 * lw_s[0][64 + lane];
            float p1 = o0 * lw_s[1][lane] + o1 * lw_s[1][64 + lane];
            float p2 = o0 * lw_s[2][lane] + o1 * lw_s[2][64 + lane];
            float p3 = o0 * lw_s[3][lane] + o1 * lw_s[3][64 + lane];
            #pragma unroll
            for (int sft = 32; sft; sft >>= 1) {
                p0 += __shfl_down(p0, sft);
                p1 += __shfl_down(p1, sft);
                p2 += __shfl_down(p2, sft);
                p3 += __shfl_down(p3, sft);
            }
            if (lane == 0) {
                proj_out[rn * 4 + 0] = p0;
                proj_out[rn * 4 + 1] = p1;
                proj_out[rn * 4 + 2] = p2;
                proj_out[rn * 4 + 3] = p3;
            }
        }

        // semantic matvec for the 4 batched rows (j = lane and lane+64)
        float s0[4] = {0.f, 0.f, 0.f, 0.f};
        float s1[4] = {0.f, 0.f, 0.f, 0.f};
        #pragma unroll 4
        for (int k = 0; k < 128; ++k) {
            float w0 = kw_s[lane][k];
            float w1 = kw_s[64 + lane][k];
            #pragma unroll
            for (int i = 0; i < 4; ++i) {
                float ov = out_s[wave][i][k];
                s0[i] += ov * w0;
                s1[i] += ov * w1;
            }
        }
        for (int i = 0; i < nvalid; ++i) {
            sem0 += tanhf(s0[i] + kb0);
            sem1 += tanhf(s1[i] + kb1);
        }
    }
    atomicAdd(&red[r * 128 + lane],      sem0);
    atomicAdd(&red[r * 128 + 64 + lane], sem1);
}

// ---------------------------------------------------------------------------
// score[r] = q . red[r] / N ; attn = softmax(score). Single wave.
// ---------------------------------------------------------------------------
__global__ void attn_kernel(const float* __restrict__ red, const float* __restrict__ q,
                            float* __restrict__ attn)
{
    int lane = threadIdx.x;
    float p[3];
    #pragma unroll
    for (int r = 0; r < 3; ++r) {
        float v = q[lane] * red[r * 128 + lane] + q[lane + 64] * red[r * 128 + lane + 64];
        for (int sft = 32; sft; sft >>= 1) v += __shfl_down(v, sft);
        p[r] = v;
    }
    if (lane == 0) {
        float s0 = p[0] / (float)N_NODES;
        float s1 = p[1] / (float)N_NODES;
        float s2 = p[2] / (float)N_NODES;
        float m = fmaxf(s0, fmaxf(s1, s2));
        float e0 = __expf(s0 - m), e1 = __expf(s1 - m), e2 = __expf(s2 - m);
        float inv = 1.f / (e0 + e1 + e2);
        attn[0] = e0 * inv; attn[1] = e1 * inv; attn[2] = e2 * inv;
    }
}

// ---------------------------------------------------------------------------
// out[n][o] = sum_r attn[r] * proj_out[r][n][o] + lb[o]
// ---------------------------------------------------------------------------
__global__ __launch_bounds__(256) void final_kernel(
    const float* __restrict__ proj_out, const float* __restrict__ attn,
    const float* __restrict__ lb, float* __restrict__ out)
{
    int i = blockIdx.x * 256 + threadIdx.x;
    if (i >= N_NODES * 4) return;
    int o = i & 3;
    float v = attn[0] * proj_out[i]
            + attn[1] * proj_out[(size_t)N_NODES * 4 + i]
            + attn[2] * proj_out[(size_t)2 * N_NODES * 4 + i]
            + lb[o];
    out[i] = v;
}

extern "C" void kernel_launch(void* const* d_in, const int* in_sizes, int n_in,
                              void* d_out, int out_size, void* d_ws, size_t ws_size,
                              hipStream_t stream)
{
    const float* x       = (const float*)d_in[0];
    const int*   e0      = (const int*)d_in[1];
    const int*   e1      = (const int*)d_in[2];
    const int*   e2      = (const int*)d_in[3];
    const float* pw      = (const float*)d_in[4];
    const float* pb      = (const float*)d_in[5];
    const float* att_src = (const float*)d_in[6];
    const float* att_dst = (const float*)d_in[7];
    const float* kw      = (const float*)d_in[8];
    const float* kb      = (const float*)d_in[9];
    const float* q       = (const float*)d_in[10];
    const float* lw      = (const float*)d_in[11];
    const float* lb      = (const float*)d_in[12];
    float* out = (float*)d_out;

    // Workspace layout (float elements). Total 22,700,512 elems = 90.8 MB.
    float* ws       = (float*)d_ws;
    float* h        = ws;                        // 12,800,000
    float* a_src    = ws + 12800000;             //  2,400,000
    float* a_dst    = ws + 15200000;             //  2,400,000
    float* proj_out = ws + 17600000;             //  1,200,000
    float* red      = ws + 18800000;             //        384
    float* attn     = ws + 18800384;             //          4
    int*   cnt      = (int*)(ws + 18800512);     //    300,000
    int*   off      = (int*)(ws + 19100512);     //    300,000
    int*   cursor   = (int*)(ws + 19400512);     //    300,000
    int*   csr_rows = (int*)(ws + 19700512);     //  3,000,000

    hipMemsetAsync(cnt, 0, 300000 * sizeof(int), stream);
    hipMemsetAsync(red, 0, 384 * sizeof(float), stream);

    proj_kernel<<<dim3(782), dim3(256), 0, stream>>>(x, pw, pb, att_src, att_dst, h, a_src, a_dst);
    count_kernel<<<dim3(3907, 3), dim3(256), 0, stream>>>(e0, e1, e2, cnt);
    scan_kernel<<<dim3(3), dim3(256), 0, stream>>>(cnt, off, cursor);
    fill_kernel<<<dim3(3907, 3), dim3(256), 0, stream>>>(e0, e1, e2, cursor, csr_rows);
    pull_kernel<<<dim3(1024, 3), dim3(256), 0, stream>>>(h, a_src, a_dst, cnt, off, csr_rows,
                                                         kw, kb, lw, proj_out, red);
    attn_kernel<<<dim3(1), dim3(64), 0, stream>>>(red, q, attn);
    final_kernel<<<dim3(1563), dim3(256), 0, stream>>>(proj_out, attn, lb, out);
}

// Round 3
// 1454.560 us; speedup vs baseline: 1.4150x; 1.4150x over previous
//
#include <hip/hip_runtime.h>

#define N_NODES 100000
#define E_EDGES 1000000
#define R_REL   3

__device__ __forceinline__ float lrelu(float x) { return x > 0.f ? x : 0.2f * x; }

// ---------------------------------------------------------------------------
// h = x @ proj_w.T + proj_b ; a_src/a_dst[r][n][hd] = <h[n,hd,:], att[r,hd,:]>
// Block: 256 threads = 2 nodes x 128 outputs, W staged in LDS (padded 129).
// ---------------------------------------------------------------------------
__global__ __launch_bounds__(256) void proj_kernel(
    const float* __restrict__ x, const float* __restrict__ pw,
    const float* __restrict__ pb, const float* __restrict__ att_src,
    const float* __restrict__ att_dst,
    float* __restrict__ h, float* __restrict__ a_src, float* __restrict__ a_dst)
{
    __shared__ float w_s[128][129];
    __shared__ float x_s[2][128];
    __shared__ float h_s[2][128];
    __shared__ float as_s[24][16];
    __shared__ float ad_s[24][16];
    __shared__ float pb_s[128];

    int tid = threadIdx.x;
    for (int i = tid; i < 128 * 128; i += 256) w_s[i >> 7][i & 127] = pw[i];
    if (tid < 128) pb_s[tid] = pb[tid];
    for (int i = tid; i < 24 * 16; i += 256) {
        as_s[i >> 4][i & 15] = att_src[i];
        ad_s[i >> 4][i & 15] = att_dst[i];
    }
    __syncthreads();

    int nn = tid >> 7, j = tid & 127;
    int nBase = blockIdx.x * 128;
    for (int it = 0; it < 64; ++it) {
        int n = nBase + it * 2 + nn;
        if (n < N_NODES) x_s[nn][j] = x[(size_t)n * 128 + j];
        __syncthreads();
        float s0 = 0.f, s1 = 0.f, s2 = 0.f, s3 = 0.f;
        #pragma unroll
        for (int k = 0; k < 128; k += 4) {
            s0 += x_s[nn][k]     * w_s[j][k];
            s1 += x_s[nn][k + 1] * w_s[j][k + 1];
            s2 += x_s[nn][k + 2] * w_s[j][k + 2];
            s3 += x_s[nn][k + 3] * w_s[j][k + 3];
        }
        float acc = ((s0 + s1) + (s2 + s3)) + pb_s[j];
        h_s[nn][j] = acc;
        if (n < N_NODES) h[(size_t)n * 128 + j] = acc;
        __syncthreads();
        if (tid < 48) {
            int nn2 = tid / 24, p = tid % 24;
            int n2 = nBase + it * 2 + nn2;
            if (n2 < N_NODES) {
                int r = p >> 3, hd = p & 7;
                float vs = 0.f, vd = 0.f;
                #pragma unroll
                for (int d = 0; d < 16; ++d) {
                    float hv = h_s[nn2][hd * 16 + d];
                    vs += hv * as_s[p][d];
                    vd += hv * ad_s[p][d];
                }
                a_src[((size_t)r * N_NODES + n2) * 8 + hd] = vs;
                a_dst[((size_t)r * N_NODES + n2) * 8 + hd] = vd;
            }
        }
        __syncthreads();
    }
}

// ---------------------------------------------------------------------------
// kwT[k][j] = kw[j][k]  (so semantic matvec reads kwT coalesced)
// ---------------------------------------------------------------------------
__global__ __launch_bounds__(256) void prep_kernel(const float* __restrict__ kw,
                                                   float* __restrict__ kwT)
{
    int i = blockIdx.x * 256 + threadIdx.x;
    if (i < 128 * 128) {
        int j = i >> 7, k = i & 127;
        kwT[k * 128 + j] = kw[i];
    }
}

// ---------------------------------------------------------------------------
// CSR build: count degrees (one int atomic per edge).
// ---------------------------------------------------------------------------
__global__ __launch_bounds__(256) void count_kernel(
    const int* __restrict__ e0, const int* __restrict__ e1, const int* __restrict__ e2,
    int* __restrict__ cnt)
{
    int r = blockIdx.y;
    const int* ei = (r == 0) ? e0 : (r == 1) ? e1 : e2;
    int e = blockIdx.x * 256 + threadIdx.x;
    if (e >= E_EDGES) return;
    int col = ei[E_EDGES + e];
    atomicAdd(&cnt[r * N_NODES + col], 1);
}

// ---------------------------------------------------------------------------
// Exclusive scan of degrees -> offsets (+cursor copy). One block per relation.
// ---------------------------------------------------------------------------
__global__ __launch_bounds__(256) void scan_kernel(
    const int* __restrict__ cnt, int* __restrict__ off, int* __restrict__ cursor)
{
    int r = blockIdx.x;
    int t = threadIdx.x;
    const int CH = (N_NODES + 255) / 256;   // 391
    int lo = t * CH, hi = lo + CH;
    if (hi > N_NODES) hi = N_NODES;
    int s = 0;
    for (int i = lo; i < hi; ++i) s += cnt[r * N_NODES + i];
    __shared__ int part[256];
    part[t] = s;
    __syncthreads();
    for (int d = 1; d < 256; d <<= 1) {
        int v = (t >= d) ? part[t - d] : 0;
        __syncthreads();
        part[t] += v;
        __syncthreads();
    }
    int base = r * E_EDGES + ((t > 0) ? part[t - 1] : 0);
    for (int i = lo; i < hi; ++i) {
        off[r * N_NODES + i] = base;
        cursor[r * N_NODES + i] = base;
        base += cnt[r * N_NODES + i];
    }
}

__global__ __launch_bounds__(256) void fill_kernel(
    const int* __restrict__ e0, const int* __restrict__ e1, const int* __restrict__ e2,
    int* __restrict__ cursor, int* __restrict__ csr_rows)
{
    int r = blockIdx.y;
    const int* ei = (r == 0) ? e0 : (r == 1) ? e1 : e2;
    int e = blockIdx.x * 256 + threadIdx.x;
    if (e >= E_EDGES) return;
    int row = ei[e];
    int col = ei[E_EDGES + e];
    int pos = atomicAdd(&cursor[r * N_NODES + col], 1);
    csr_rows[pos] = row;
}

// ---------------------------------------------------------------------------
// Fused pull + semantic + lin projection. One wave handles 4 node streams
// INTERLEAVED (branch-free predication, row-index prefetch) for 4x MLP.
// LDS is only out_s (8 KB) + lw/kb -> occupancy VGPR-limited, not LDS-limited.
// Semantic matvec reads pre-transposed kwT coalesced from L1/L2.
// ---------------------------------------------------------------------------
__global__ __launch_bounds__(256) void pull_kernel(
    const float* __restrict__ h, const float* __restrict__ a_src,
    const float* __restrict__ a_dst, const int* __restrict__ cnt,
    const int* __restrict__ off, const int* __restrict__ csr_rows,
    const float* __restrict__ kwT, const float* __restrict__ kb,
    const float* __restrict__ lw,
    float* __restrict__ proj_out, float* __restrict__ red)
{
    __shared__ float out_s[4][4][128];
    __shared__ float lw_s[4][128];
    __shared__ float kb_s[128];

    int tid = threadIdx.x;
    int r = blockIdx.y;
    for (int i = tid; i < 512; i += 256) lw_s[i >> 7][i & 127] = lw[i];
    if (tid < 128) kb_s[tid] = kb[tid];
    __syncthreads();

    int wave = tid >> 6, lane = tid & 63;
    int h0 = lane >> 4, h1 = h0 + 4;
    float kb0 = kb_s[lane], kb1 = kb_s[64 + lane];
    float sem0 = 0.f, sem1 = 0.f;
    const size_t rbase = (size_t)r * N_NODES;
    const int CSR_LAST = R_REL * E_EDGES - 1;

    for (int nb = blockIdx.x * 16 + wave * 4; nb < N_NODES; nb += gridDim.x * 16) {
        // ---- prologue: 4 independent node streams ----
        int   deg4[4], st4[4];
        float ad0v[4], ad1v[4];
        float a0v[4] = {0.f,0.f,0.f,0.f}, a1v[4] = {0.f,0.f,0.f,0.f};
        float d0v[4] = {0.f,0.f,0.f,0.f}, d1v[4] = {0.f,0.f,0.f,0.f};
        int kmax = 0;
        #pragma unroll
        for (int i = 0; i < 4; ++i) {
            int n = nb + i;
            int nc = (n < N_NODES) ? n : (N_NODES - 1);
            size_t rn = rbase + nc;
            int d = (n < N_NODES) ? cnt[rn] : 0;
            deg4[i] = d;
            st4[i]  = off[rn];
            ad0v[i] = a_dst[rn * 8 + h0];
            ad1v[i] = a_dst[rn * 8 + h1];
            kmax = (d > kmax) ? d : kmax;
        }
        // prefetch row indices for k=0 (clamped; csr_rows is dense/valid)
        int row4[4];
        #pragma unroll
        for (int i = 0; i < 4; ++i)
            row4[i] = csr_rows[min(st4[i], CSR_LAST)];

        // ---- branch-free interleaved edge loop ----
        for (int k = 0; k < kmax; ++k) {
            int nrow[4];
            #pragma unroll
            for (int i = 0; i < 4; ++i) {          // prefetch k+1's rows
                int dm1 = deg4[i] - 1; if (dm1 < 0) dm1 = 0;
                int kk = k + 1; if (kk > dm1) kk = dm1;
                nrow[i] = csr_rows[min(st4[i] + kk, CSR_LAST)];
            }
            #pragma unroll
            for (int i = 0; i < 4; ++i) {
                float live = (k < deg4[i]) ? 1.f : 0.f;
                int row = row4[i];
                size_t rr = rbase + row;
                float e0 = live * __expf(lrelu(a_src[rr * 8 + h0] + ad0v[i]));
                float e1 = live * __expf(lrelu(a_src[rr * 8 + h1] + ad1v[i]));
                const float* hr = h + (size_t)row * 128;
                a0v[i] += e0 * hr[lane];
                a1v[i] += e1 * hr[64 + lane];
                d0v[i] += e0;
                d1v[i] += e1;
            }
            #pragma unroll
            for (int i = 0; i < 4; ++i) row4[i] = nrow[i];
        }

        // ---- finish rows: relu(acc/den), lin proj, stash for semantic ----
        #pragma unroll
        for (int i = 0; i < 4; ++i) {
            float o0 = fmaxf(a0v[i] / (d0v[i] + 1e-16f), 0.f);
            float o1 = fmaxf(a1v[i] / (d1v[i] + 1e-16f), 0.f);
            out_s[wave][i][lane]      = o0;
            out_s[wave][i][64 + lane] = o1;
            float p0 = o0 * lw_s[0][lane] + o1 * lw_s[0][64 + lane];
            float p1 = o0 * lw_s[1][lane] + o1 * lw_s[1][64 + lane];
            float p2 = o0 * lw_s[2][lane] + o1 * lw_s[2][64 + lane];
            float p3 = o0 * lw_s[3][lane] + o1 * lw_s[3][64 + lane];
            #pragma unroll
            for (int sft = 32; sft; sft >>= 1) {
                p0 += __shfl_down(p0, sft);
                p1 += __shfl_down(p1, sft);
                p2 += __shfl_down(p2, sft);
                p3 += __shfl_down(p3, sft);
            }
            if (lane == 0 && nb + i < N_NODES) {
                size_t rn = rbase + nb + i;
                proj_out[rn * 4 + 0] = p0;
                proj_out[rn * 4 + 1] = p1;
                proj_out[rn * 4 + 2] = p2;
                proj_out[rn * 4 + 3] = p3;
            }
        }

        // ---- semantic matvec: s[i][j] = out_i . kw[j]  (kwT coalesced) ----
        float s0[4] = {0.f,0.f,0.f,0.f}, s1[4] = {0.f,0.f,0.f,0.f};
        #pragma unroll 4
        for (int k = 0; k < 128; ++k) {
            float w0 = kwT[k * 128 + lane];
            float w1 = kwT[k * 128 + 64 + lane];
            #pragma unroll
            for (int i = 0; i < 4; ++i) {
                float ov = out_s[wave][i][k];
                s0[i] += ov * w0;
                s1[i] += ov * w1;
            }
        }
        int nvalid = N_NODES - nb; if (nvalid > 4) nvalid = 4;
        #pragma unroll
        for (int i = 0; i < 4; ++i) {
            if (i < nvalid) {
                sem0 += tanhf(s0[i] + kb0);
                sem1 += tanhf(s1[i] + kb1);
            }
        }
    }
    atomicAdd(&red[r * 128 + lane],      sem0);
    atomicAdd(&red[r * 128 + 64 + lane], sem1);
}

// ---------------------------------------------------------------------------
// score[r] = q . red[r] / N ; attn = softmax(score). Single wave.
// ---------------------------------------------------------------------------
__global__ void attn_kernel(const float* __restrict__ red, const float* __restrict__ q,
                            float* __restrict__ attn)
{
    int lane = threadIdx.x;
    float p[3];
    #pragma unroll
    for (int r = 0; r < 3; ++r) {
        float v = q[lane] * red[r * 128 + lane] + q[lane + 64] * red[r * 128 + lane + 64];
        for (int sft = 32; sft; sft >>= 1) v += __shfl_down(v, sft);
        p[r] = v;
    }
    if (lane == 0) {
        float s0 = p[0] / (float)N_NODES;
        float s1 = p[1] / (float)N_NODES;
        float s2 = p[2] / (float)N_NODES;
        float m = fmaxf(s0, fmaxf(s1, s2));
        float e0 = __expf(s0 - m), e1 = __expf(s1 - m), e2 = __expf(s2 - m);
        float inv = 1.f / (e0 + e1 + e2);
        attn[0] = e0 * inv; attn[1] = e1 * inv; attn[2] = e2 * inv;
    }
}

// ---------------------------------------------------------------------------
// out[n][o] = sum_r attn[r] * proj_out[r][n][o] + lb[o]
// ---------------------------------------------------------------------------
__global__ __launch_bounds__(256) void final_kernel(
    const float* __restrict__ proj_out, const float* __restrict__ attn,
    const float* __restrict__ lb, float* __restrict__ out)
{
    int i = blockIdx.x * 256 + threadIdx.x;
    if (i >= N_NODES * 4) return;
    int o = i & 3;
    float v = attn[0] * proj_out[i]
            + attn[1] * proj_out[(size_t)N_NODES * 4 + i]
            + attn[2] * proj_out[(size_t)2 * N_NODES * 4 + i]
            + lb[o];
    out[i] = v;
}

extern "C" void kernel_launch(void* const* d_in, const int* in_sizes, int n_in,
                              void* d_out, int out_size, void* d_ws, size_t ws_size,
                              hipStream_t stream)
{
    const float* x       = (const float*)d_in[0];
    const int*   e0      = (const int*)d_in[1];
    const int*   e1      = (const int*)d_in[2];
    const int*   e2      = (const int*)d_in[3];
    const float* pw      = (const float*)d_in[4];
    const float* pb      = (const float*)d_in[5];
    const float* att_src = (const float*)d_in[6];
    const float* att_dst = (const float*)d_in[7];
    const float* kw      = (const float*)d_in[8];
    const float* kb      = (const float*)d_in[9];
    const float* q       = (const float*)d_in[10];
    const float* lw      = (const float*)d_in[11];
    const float* lb      = (const float*)d_in[12];
    float* out = (float*)d_out;

    // Workspace layout (float elements). Total ~90.9 MB.
    float* ws       = (float*)d_ws;
    float* h        = ws;                        // 12,800,000
    float* a_src    = ws + 12800000;             //  2,400,000
    float* a_dst    = ws + 15200000;             //  2,400,000
    float* proj_out = ws + 17600000;             //  1,200,000
    float* red      = ws + 18800000;             //        384
    float* attn     = ws + 18800384;             //          4
    float* kwT      = ws + 18800512;             //     16,384
    int*   cnt      = (int*)(ws + 18816896);     //    300,000
    int*   off      = (int*)(ws + 19116896);     //    300,000
    int*   cursor   = (int*)(ws + 19416896);     //    300,000
    int*   csr_rows = (int*)(ws + 19716896);     //  3,000,000

    hipMemsetAsync(cnt, 0, 300000 * sizeof(int), stream);
    hipMemsetAsync(red, 0, 384 * sizeof(float), stream);

    proj_kernel<<<dim3(782), dim3(256), 0, stream>>>(x, pw, pb, att_src, att_dst, h, a_src, a_dst);
    prep_kernel<<<dim3(64), dim3(256), 0, stream>>>(kw, kwT);
    count_kernel<<<dim3(3907, 3), dim3(256), 0, stream>>>(e0, e1, e2, cnt);
    scan_kernel<<<dim3(3), dim3(256), 0, stream>>>(cnt, off, cursor);
    fill_kernel<<<dim3(3907, 3), dim3(256), 0, stream>>>(e0, e1, e2, cursor, csr_rows);
    pull_kernel<<<dim3(1563, 3), dim3(256), 0, stream>>>(h, a_src, a_dst, cnt, off, csr_rows,
                                                         kwT, kb, lw, proj_out, red);
    attn_kernel<<<dim3(1), dim3(64), 0, stream>>>(red, q, attn);
    final_kernel<<<dim3(1563), dim3(256), 0, stream>>>(proj_out, attn, lb, out);
}